// Round 6
// baseline (18.677 us; speedup 1.0000x reference)
//
#include <hip/hip_runtime.h>

#define NLAY 8

// One wave (64 threads) per block, fully self-contained: no cross-wave
// barriers. Each block handles 256 samples (4/lane).
//   out[b][m] = 0.5 + sum_{p,q} M_m[p][q] * G01[p] * G23[q]
// where M folds A_m = sum_k w_k U_k^T D_m U_k + w4 D_m (sqrt(w_k) pre-folded
// into the stored U columns), G01/G23 are the 10 symmetric products of the
// per-qubit-pair RY amplitudes.
__global__ __launch_bounds__(64) void qnn_wave(const float4* __restrict__ x,
                                               const float* __restrict__ alpha,
                                               const float* __restrict__ thetas,
                                               float* __restrict__ out,
                                               int batch) {
    __shared__ float2 csT[128];       // (cos,sin) of thetas/2
    __shared__ float2 csA[8];         // (cos,sin) of alpha/2
    __shared__ float  U[4][16][20];   // sqrt(w_k)-scaled columns, padded rows
    __shared__ float  Af[3][16][16];  // full symmetric A_m
    __shared__ float  Mf[3][10][12];  // folded 10x10, padded to 12

    const int lane = threadIdx.x;     // 0..63
    const int base = blockIdx.x * 256;

    // ---- prefetch this lane's 4 samples (latency hides under setup) ----
    float4 xv[4];
    #pragma unroll
    for (int s = 0; s < 4; ++s) {
        const int b = base + s * 64 + lane;
        xv[s] = x[(b < batch) ? b : 0];
    }

    // ---- phase 0: angle tables ----
    {
        const float t0 = thetas[lane] * 0.5f;
        const float t1 = thetas[64 + lane] * 0.5f;
        csT[lane]      = make_float2(cosf(t0), sinf(t0));
        csT[64 + lane] = make_float2(cosf(t1), sinf(t1));
        if (lane < 7) {
            const float ta = alpha[lane] * 0.5f;
            csA[lane] = make_float2(cosf(ta), sinf(ta));
        }
    }
    __syncthreads();   // 1-wave block: compiles to waitcnt (+cheap barrier)

    // ---- ancilla weights, redundant per lane (~40 VALU) ----
    float w0, w1, w2, w3, w4;
    {
        float e[8];
        #pragma unroll
        for (int i = 0; i < 8; ++i) e[i] = (i == 0) ? 1.0f : 0.0f;
        int idx = 0;
        #pragma unroll
        for (int l = 0; l < 3; ++l) {
            const int p = 2 - l, pb = 1 << p;
            #pragma unroll
            for (int i0 = 0; i0 < 8; ++i0) {
                if (i0 & pb) continue;
                const int i1 = i0 | pb;
                const float2 cs = csA[idx + (i0 >> (p + 1))];
                const float a0 = e[i0], a1 = e[i1];
                e[i0] = cs.x * a0 - cs.y * a1;
                e[i1] = cs.y * a0 + cs.x * a1;
            }
            idx += (1 << l);
        }
        w0 = e[0]*e[0]; w1 = e[1]*e[1]; w2 = e[2]*e[2]; w3 = e[3]*e[3];
        w4 = e[4]*e[4] + e[5]*e[5] + e[6]*e[6] + e[7]*e[7];
    }

    // ---- phase 1: lane (k,col) simulates one scaled column ----
    {
        const int k = lane >> 4, col = lane & 15;
        float st[16];
        #pragma unroll
        for (int i = 0; i < 16; ++i) st[i] = (i == col) ? 1.0f : 0.0f;
        #pragma unroll 1
        for (int l = 0; l < NLAY; ++l) {
            #pragma unroll
            for (int q = 0; q < 4; ++q) {
                const float2 cs = csT[k * 32 + l * 4 + q];
                const int pb = 1 << (3 - q);
                #pragma unroll
                for (int i0 = 0; i0 < 16; ++i0) {
                    if (i0 & pb) continue;
                    const int i1 = i0 | pb;
                    const float a0 = st[i0], a1 = st[i1];
                    st[i0] = cs.x * a0 - cs.y * a1;   // RY = [[c,-s],[s,c]]
                    st[i1] = cs.y * a0 + cs.x * a1;
                }
            }
            #pragma unroll
            for (int q = 0; q < 3; ++q) {   // CNOT(q,q+1): register renames
                const int cb = 1 << (3 - q), tb = 1 << (2 - q);
                #pragma unroll
                for (int i = 0; i < 16; ++i) {
                    if ((i & cb) && !(i & tb)) {
                        const int j = i | tb;
                        const float tmp = st[i]; st[i] = st[j]; st[j] = tmp;
                    }
                }
            }
        }
        const float sw = sqrtf((k == 0) ? w0 : (k == 1) ? w1 : (k == 2) ? w2 : w3);
        float4* dst = (float4*)&U[k][col][0];
        dst[0] = make_float4(st[0]*sw,  st[1]*sw,  st[2]*sw,  st[3]*sw);
        dst[1] = make_float4(st[4]*sw,  st[5]*sw,  st[6]*sw,  st[7]*sw);
        dst[2] = make_float4(st[8]*sw,  st[9]*sw,  st[10]*sw, st[11]*sw);
        dst[3] = make_float4(st[12]*sw, st[13]*sw, st[14]*sw, st[15]*sw);
    }
    __syncthreads();

    // ---- phase 2a: gram matrix in 2x2 blocks (36 jobs, one round) ----
    if (lane < 36) {
        int r = lane, T = 0;
        while (r >= 8 - T) { r -= 8 - T; ++T; }
        const int V = T + r;

        float gs[2][2][8] = {};
        #pragma unroll
        for (int k = 0; k < 4; ++k) {
            float a[2][16], c[2][16];
            #pragma unroll
            for (int d = 0; d < 2; ++d) {
                const float4* ct = (const float4*)&U[k][2*T + d][0];
                const float4* cu = (const float4*)&U[k][2*V + d][0];
                #pragma unroll
                for (int v = 0; v < 4; ++v) {
                    const float4 av = ct[v], cv = cu[v];
                    a[d][4*v+0] = av.x; a[d][4*v+1] = av.y;
                    a[d][4*v+2] = av.z; a[d][4*v+3] = av.w;
                    c[d][4*v+0] = cv.x; c[d][4*v+1] = cv.y;
                    c[d][4*v+2] = cv.z; c[d][4*v+3] = cv.w;
                }
            }
            #pragma unroll
            for (int dt = 0; dt < 2; ++dt)
                #pragma unroll
                for (int du = 0; du < 2; ++du)
                    #pragma unroll
                    for (int rr = 0; rr < 16; ++rr)
                        gs[dt][du][rr >> 1] =
                            fmaf(a[dt][rr], c[du][rr], gs[dt][du][rr >> 1]);
        }
        #pragma unroll
        for (int dt = 0; dt < 2; ++dt) {
            #pragma unroll
            for (int du = 0; du < 2; ++du) {
                const int t = 2*T + dt, u = 2*V + du;
                float A0 = 0.f, A1 = 0.f, A2 = 0.f;
                #pragma unroll
                for (int cc = 0; cc < 8; ++cc) {
                    const float g = gs[dt][du][cc];
                    A0 += (cc & 4) ? -g : g;
                    A1 += (cc & 2) ? -g : g;
                    A2 += (cc & 1) ? -g : g;
                }
                if (t == u) {
                    A0 += ((t >> 3) & 1) ? -w4 : w4;
                    A1 += ((t >> 2) & 1) ? -w4 : w4;
                    A2 += ((t >> 1) & 1) ? -w4 : w4;
                }
                Af[0][t][u] = A0; Af[0][u][t] = A0;
                Af[1][t][u] = A1; Af[1][u][t] = A1;
                Af[2][t][u] = A2; Af[2][u][t] = A2;
            }
        }
    }
    __syncthreads();

    // ---- phase 2b: fold to Mf[3][10][12] (pads written as 0) ----
    #pragma unroll 1
    for (int round = 0; round < 6; ++round) {
        const int e = round * 64 + lane;
        if (e < 360) {
            const int m = e / 120, rr = e - m * 120, p = rr / 12, q = rr - p * 12;
            float v = 0.0f;
            if (q < 10) {
                int i, k, jj, ll;
                if (p < 4)      { i = 0; k = p; }
                else if (p < 7) { i = 1; k = p - 3; }
                else if (p < 9) { i = 2; k = p - 5; }
                else            { i = 3; k = 3; }
                if (q < 4)      { jj = 0; ll = q; }
                else if (q < 7) { jj = 1; ll = q - 3; }
                else if (q < 9) { jj = 2; ll = q - 5; }
                else            { jj = 3; ll = 3; }
                if (i < k && jj < ll)       v = Af[m][4*i+jj][4*k+ll] + Af[m][4*i+ll][4*k+jj];
                else if (i == k && jj < ll) v = Af[m][4*i+jj][4*i+ll];
                else if (i < k && jj == ll) v = Af[m][4*i+jj][4*k+jj];
                else                        v = 0.5f * Af[m][4*i+jj][4*i+jj];
            }
            Mf[m][p][q] = v;
        }
    }
    __syncthreads();

    // ---- phase 3: 4 samples per lane ----
    float G01[4][10], G23[4][10], acc[4][3];
    #pragma unroll
    for (int s = 0; s < 4; ++s) {
        float c0, s0, c1, s1, c2, s2, c3, s3;
        sincospif(xv[s].x, &s0, &c0);
        sincospif(xv[s].y, &s1, &c1);
        sincospif(xv[s].z, &s2, &c2);
        sincospif(xv[s].w, &s3, &c3);
        float f01[4], f23[4];
        f01[0] = c0 * c1; f01[1] = c0 * s1; f01[2] = s0 * c1; f01[3] = s0 * s1;
        f23[0] = c2 * c3; f23[1] = c2 * s3; f23[2] = s2 * c3; f23[3] = s2 * s3;
        int idx = 0;
        #pragma unroll
        for (int i = 0; i < 4; ++i)
            #pragma unroll
            for (int k = i; k < 4; ++k) { G01[s][idx] = f01[i] * f01[k]; ++idx; }
        idx = 0;
        #pragma unroll
        for (int j = 0; j < 4; ++j)
            #pragma unroll
            for (int l = j; l < 4; ++l) { G23[s][idx] = f23[j] * f23[l]; ++idx; }
        acc[s][0] = 0.5f; acc[s][1] = 0.5f; acc[s][2] = 0.5f;
    }

    #pragma unroll
    for (int m = 0; m < 3; ++m) {
        #pragma unroll
        for (int p = 0; p < 10; ++p) {
            const float4* row = (const float4*)&Mf[m][p][0];
            const float4 r0 = row[0], r1 = row[1], r2 = row[2];
            #pragma unroll
            for (int s = 0; s < 4; ++s) {
                float z;
                z = r0.x * G23[s][0];
                z = fmaf(r0.y, G23[s][1], z);
                z = fmaf(r0.z, G23[s][2], z);
                z = fmaf(r0.w, G23[s][3], z);
                z = fmaf(r1.x, G23[s][4], z);
                z = fmaf(r1.y, G23[s][5], z);
                z = fmaf(r1.z, G23[s][6], z);
                z = fmaf(r1.w, G23[s][7], z);
                z = fmaf(r2.x, G23[s][8], z);
                z = fmaf(r2.y, G23[s][9], z);
                acc[s][m] = fmaf(G01[s][p], z, acc[s][m]);
            }
        }
    }

    #pragma unroll
    for (int s = 0; s < 4; ++s) {
        const int b = base + s * 64 + lane;
        if (b < batch) {
            out[b * 3 + 0] = acc[s][0];
            out[b * 3 + 1] = acc[s][1];
            out[b * 3 + 2] = acc[s][2];
        }
    }
}

extern "C" void kernel_launch(void* const* d_in, const int* in_sizes, int n_in,
                              void* d_out, int out_size, void* d_ws, size_t ws_size,
                              hipStream_t stream) {
    const float* x      = (const float*)d_in[0];   // (131072, 4) f32
    const float* alpha  = (const float*)d_in[1];   // (7,) f32
    const float* thetas = (const float*)d_in[2];   // (4, 32) f32

    const int batch = in_sizes[0] / 4;             // 131072
    const int blocks = (batch + 255) / 256;        // 512 blocks x 64 threads
    qnn_wave<<<blocks, 64, 0, stream>>>((const float4*)x, alpha, thetas,
                                        (float*)d_out, batch);
}

// Round 7
// 14.319 us; speedup vs baseline: 1.3043x; 1.3043x over previous
//
#include <hip/hip_runtime.h>

#define NLAY 8
#define TPB 256
#define SPT 2

// Single fused kernel, R4 structure with latency-oriented phase 3.
//   out[b][m] = 0.5 + sum_{p,q} M_m[p][q] * G01[p] * G23[q]
// M folds A_m = sum_k w_k U_k^T D_m U_k + w4 D_m (e[k] pre-folded into the
// stored U columns; sign cancels in products), G01/G23 are the 10 symmetric
// products of the per-qubit-pair RY amplitudes.
__global__ __launch_bounds__(TPB) void qnn_fused(const float4* __restrict__ x,
                                                 const float* __restrict__ alpha,
                                                 const float* __restrict__ thetas,
                                                 float* __restrict__ out,
                                                 int batch, int nthreads) {
    __shared__ float2 csT[128];       // (cos,sin) of thetas/2
    __shared__ float2 csA[8];         // (cos,sin) of alpha/2
    __shared__ float  U[4][16][20];   // e[k]-scaled columns, rows padded to 20
    __shared__ float  w4s;            // tail weight sum
    __shared__ float  Af[3][16][16];  // full symmetric A_m
    __shared__ float  Mf[3][10][12];  // folded 10x10, q padded to 12

    const int tid = threadIdx.x;
    const int gid = blockIdx.x * TPB + tid;

    // ---- prefetch this thread's samples (HBM latency hides under setup) ----
    float4 xv[SPT];
    #pragma unroll
    for (int s = 0; s < SPT; ++s) {
        const int b = gid + s * nthreads;
        xv[s] = x[(b < batch) ? b : 0];
    }

    // ---- phase 0: angle tables ----
    if (tid < 128) {
        const float t = thetas[tid] * 0.5f;
        csT[tid] = make_float2(cosf(t), sinf(t));
    } else if (tid < 135) {
        const float t = alpha[tid - 128] * 0.5f;
        csA[tid - 128] = make_float2(cosf(t), sinf(t));
    }
    __syncthreads();

    // ---- phase 1: lanes 0..63 simulate one scaled column each ----
    if (tid < 64) {
        // ancilla amplitudes, computed redundantly per lane (~24 VALU)
        float e[8];
        #pragma unroll
        for (int i = 0; i < 8; ++i) e[i] = (i == 0) ? 1.0f : 0.0f;
        int idx = 0;
        #pragma unroll
        for (int l = 0; l < 3; ++l) {
            const int p = 2 - l, pb = 1 << p;
            #pragma unroll
            for (int i0 = 0; i0 < 8; ++i0) {
                if (i0 & pb) continue;
                const int i1 = i0 | pb;
                const float2 cs = csA[idx + (i0 >> (p + 1))];
                const float a0 = e[i0], a1 = e[i1];
                e[i0] = cs.x * a0 - cs.y * a1;
                e[i1] = cs.y * a0 + cs.x * a1;
            }
            idx += (1 << l);
        }
        if (tid == 0)
            w4s = e[4]*e[4] + e[5]*e[5] + e[6]*e[6] + e[7]*e[7];

        const int k = tid >> 4, col = tid & 15;
        float st[16];
        #pragma unroll
        for (int i = 0; i < 16; ++i) st[i] = (i == col) ? 1.0f : 0.0f;
        #pragma unroll 1
        for (int l = 0; l < NLAY; ++l) {
            #pragma unroll
            for (int q = 0; q < 4; ++q) {
                const float2 cs = csT[k * 32 + l * 4 + q];
                const int pb = 1 << (3 - q);
                #pragma unroll
                for (int i0 = 0; i0 < 16; ++i0) {
                    if (i0 & pb) continue;
                    const int i1 = i0 | pb;
                    const float a0 = st[i0], a1 = st[i1];
                    st[i0] = cs.x * a0 - cs.y * a1;   // RY = [[c,-s],[s,c]]
                    st[i1] = cs.y * a0 + cs.x * a1;
                }
            }
            #pragma unroll
            for (int q = 0; q < 3; ++q) {   // CNOT(q,q+1): register renames
                const int cb = 1 << (3 - q), tb = 1 << (2 - q);
                #pragma unroll
                for (int i = 0; i < 16; ++i) {
                    if ((i & cb) && !(i & tb)) {
                        const int j = i | tb;
                        const float tmp = st[i]; st[i] = st[j]; st[j] = tmp;
                    }
                }
            }
        }
        const float sw = e[k];   // sign cancels in products
        float4* dst = (float4*)&U[k][col][0];
        dst[0] = make_float4(st[0]*sw,  st[1]*sw,  st[2]*sw,  st[3]*sw);
        dst[1] = make_float4(st[4]*sw,  st[5]*sw,  st[6]*sw,  st[7]*sw);
        dst[2] = make_float4(st[8]*sw,  st[9]*sw,  st[10]*sw, st[11]*sw);
        dst[3] = make_float4(st[12]*sw, st[13]*sw, st[14]*sw, st[15]*sw);
    }
    __syncthreads();

    // ---- phase 2a: symmetric A_m, 136 jobs, pure fma on float4 column reads ----
    if (tid < 136) {
        int r = tid, t = 0;
        while (r >= 16 - t) { r -= 16 - t; ++t; }
        const int u = t + r;

        float gs[8] = {0,0,0,0,0,0,0,0};
        #pragma unroll
        for (int k = 0; k < 4; ++k) {
            const float4* ct = (const float4*)&U[k][t][0];
            const float4* cu = (const float4*)&U[k][u][0];
            const float4 a0 = ct[0], a1 = ct[1], a2 = ct[2], a3 = ct[3];
            const float4 c0 = cu[0], c1 = cu[1], c2 = cu[2], c3 = cu[3];
            gs[0] = fmaf(a0.x, c0.x, gs[0]); gs[0] = fmaf(a0.y, c0.y, gs[0]);
            gs[1] = fmaf(a0.z, c0.z, gs[1]); gs[1] = fmaf(a0.w, c0.w, gs[1]);
            gs[2] = fmaf(a1.x, c1.x, gs[2]); gs[2] = fmaf(a1.y, c1.y, gs[2]);
            gs[3] = fmaf(a1.z, c1.z, gs[3]); gs[3] = fmaf(a1.w, c1.w, gs[3]);
            gs[4] = fmaf(a2.x, c2.x, gs[4]); gs[4] = fmaf(a2.y, c2.y, gs[4]);
            gs[5] = fmaf(a2.z, c2.z, gs[5]); gs[5] = fmaf(a2.w, c2.w, gs[5]);
            gs[6] = fmaf(a3.x, c3.x, gs[6]); gs[6] = fmaf(a3.y, c3.y, gs[6]);
            gs[7] = fmaf(a3.z, c3.z, gs[7]); gs[7] = fmaf(a3.w, c3.w, gs[7]);
        }
        float A0 = 0.f, A1 = 0.f, A2 = 0.f;
        #pragma unroll
        for (int c = 0; c < 8; ++c) {
            const float g = gs[c];
            A0 += (c & 4) ? -g : g;
            A1 += (c & 2) ? -g : g;
            A2 += (c & 1) ? -g : g;
        }
        if (t == u) {
            const float w4 = w4s;
            A0 += ((t >> 3) & 1) ? -w4 : w4;
            A1 += ((t >> 2) & 1) ? -w4 : w4;
            A2 += ((t >> 1) & 1) ? -w4 : w4;
        }
        Af[0][t][u] = A0; Af[0][u][t] = A0;
        Af[1][t][u] = A1; Af[1][u][t] = A1;
        Af[2][t][u] = A2; Af[2][u][t] = A2;
    }
    __syncthreads();

    // ---- phase 2b: fold to Mf[3][10][12] (pads written as 0) ----
    for (int e = tid; e < 360; e += TPB) {
        const int m = e / 120, rr = e - m * 120, p = rr / 12, q = rr - p * 12;
        float v = 0.0f;
        if (q < 10) {
            int i, k, jj, ll;
            if (p < 4)      { i = 0; k = p; }
            else if (p < 7) { i = 1; k = p - 3; }
            else if (p < 9) { i = 2; k = p - 5; }
            else            { i = 3; k = 3; }
            if (q < 4)      { jj = 0; ll = q; }
            else if (q < 7) { jj = 1; ll = q - 3; }
            else if (q < 9) { jj = 2; ll = q - 5; }
            else            { jj = 3; ll = 3; }
            if (i < k && jj < ll)       v = Af[m][4*i+jj][4*k+ll] + Af[m][4*i+ll][4*k+jj];
            else if (i == k && jj < ll) v = Af[m][4*i+jj][4*i+ll];
            else if (i < k && jj == ll) v = Af[m][4*i+jj][4*k+jj];
            else                        v = 0.5f * Af[m][4*i+jj][4*i+jj];
        }
        Mf[m][p][q] = v;
    }
    __syncthreads();

    // ---- phase 3: SPT samples/thread; 9 batched loads + 6 chains per p ----
    float G01[SPT][10], G23[SPT][10], acc[SPT][3];
    #pragma unroll
    for (int s = 0; s < SPT; ++s) {
        float c0, s0, c1, s1, c2, s2, c3, s3;
        sincospif(xv[s].x, &s0, &c0);
        sincospif(xv[s].y, &s1, &c1);
        sincospif(xv[s].z, &s2, &c2);
        sincospif(xv[s].w, &s3, &c3);
        float f01[4], f23[4];
        f01[0] = c0 * c1; f01[1] = c0 * s1; f01[2] = s0 * c1; f01[3] = s0 * s1;
        f23[0] = c2 * c3; f23[1] = c2 * s3; f23[2] = s2 * c3; f23[3] = s2 * s3;
        int idx = 0;
        #pragma unroll
        for (int i = 0; i < 4; ++i)
            #pragma unroll
            for (int k = i; k < 4; ++k) { G01[s][idx] = f01[i] * f01[k]; ++idx; }
        idx = 0;
        #pragma unroll
        for (int j = 0; j < 4; ++j)
            #pragma unroll
            for (int l = j; l < 4; ++l) { G23[s][idx] = f23[j] * f23[l]; ++idx; }
        acc[s][0] = 0.5f; acc[s][1] = 0.5f; acc[s][2] = 0.5f;
    }

    #pragma unroll
    for (int p = 0; p < 10; ++p) {
        // batch all 9 row loads -> 9 outstanding ds_reads overlap compute
        const float4 m00 = *(const float4*)&Mf[0][p][0];
        const float4 m01 = *(const float4*)&Mf[0][p][4];
        const float4 m02 = *(const float4*)&Mf[0][p][8];
        const float4 m10 = *(const float4*)&Mf[1][p][0];
        const float4 m11 = *(const float4*)&Mf[1][p][4];
        const float4 m12 = *(const float4*)&Mf[1][p][8];
        const float4 m20 = *(const float4*)&Mf[2][p][0];
        const float4 m21 = *(const float4*)&Mf[2][p][4];
        const float4 m22 = *(const float4*)&Mf[2][p][8];
        #pragma unroll
        for (int s = 0; s < SPT; ++s) {   // 6 independent chains (3m x 2s)
            float z0, z1, z2;
            z0 = m00.x * G23[s][0];
            z1 = m10.x * G23[s][0];
            z2 = m20.x * G23[s][0];
            z0 = fmaf(m00.y, G23[s][1], z0);
            z1 = fmaf(m10.y, G23[s][1], z1);
            z2 = fmaf(m20.y, G23[s][1], z2);
            z0 = fmaf(m00.z, G23[s][2], z0);
            z1 = fmaf(m10.z, G23[s][2], z1);
            z2 = fmaf(m20.z, G23[s][2], z2);
            z0 = fmaf(m00.w, G23[s][3], z0);
            z1 = fmaf(m10.w, G23[s][3], z1);
            z2 = fmaf(m20.w, G23[s][3], z2);
            z0 = fmaf(m01.x, G23[s][4], z0);
            z1 = fmaf(m11.x, G23[s][4], z1);
            z2 = fmaf(m21.x, G23[s][4], z2);
            z0 = fmaf(m01.y, G23[s][5], z0);
            z1 = fmaf(m11.y, G23[s][5], z1);
            z2 = fmaf(m21.y, G23[s][5], z2);
            z0 = fmaf(m01.z, G23[s][6], z0);
            z1 = fmaf(m11.z, G23[s][6], z1);
            z2 = fmaf(m21.z, G23[s][6], z2);
            z0 = fmaf(m01.w, G23[s][7], z0);
            z1 = fmaf(m11.w, G23[s][7], z1);
            z2 = fmaf(m21.w, G23[s][7], z2);
            z0 = fmaf(m02.x, G23[s][8], z0);
            z1 = fmaf(m12.x, G23[s][8], z1);
            z2 = fmaf(m22.x, G23[s][8], z2);
            z0 = fmaf(m02.y, G23[s][9], z0);
            z1 = fmaf(m12.y, G23[s][9], z1);
            z2 = fmaf(m22.y, G23[s][9], z2);
            acc[s][0] = fmaf(G01[s][p], z0, acc[s][0]);
            acc[s][1] = fmaf(G01[s][p], z1, acc[s][1]);
            acc[s][2] = fmaf(G01[s][p], z2, acc[s][2]);
        }
    }

    #pragma unroll
    for (int s = 0; s < SPT; ++s) {
        const int b = gid + s * nthreads;
        if (b < batch) {
            out[b * 3 + 0] = acc[s][0];
            out[b * 3 + 1] = acc[s][1];
            out[b * 3 + 2] = acc[s][2];
        }
    }
}

extern "C" void kernel_launch(void* const* d_in, const int* in_sizes, int n_in,
                              void* d_out, int out_size, void* d_ws, size_t ws_size,
                              hipStream_t stream) {
    const float* x      = (const float*)d_in[0];   // (131072, 4) f32
    const float* alpha  = (const float*)d_in[1];   // (7,) f32
    const float* thetas = (const float*)d_in[2];   // (4, 32) f32

    const int batch = in_sizes[0] / 4;                         // 131072
    const int blocks = (batch + TPB * SPT - 1) / (TPB * SPT);  // 256
    const int nthreads = blocks * TPB;
    qnn_fused<<<blocks, TPB, 0, stream>>>((const float4*)x, alpha, thetas,
                                          (float*)d_out, batch, nthreads);
}

// Round 9
// 12.954 us; speedup vs baseline: 1.4418x; 1.1054x over previous
//
#include <hip/hip_runtime.h>

typedef __fp16 half2_t __attribute__((ext_vector_type(2)));

#define NLAY 8
#define TPB 256
#define SPT 2

static __device__ __forceinline__ half2_t bch(int v) {
    return __builtin_bit_cast(half2_t, v);
}

// Single fused kernel (R7 structure). Phase 3 contracts f16-packed M with
// v_dot2_f32_f16 (2 MACs/instr, f32 accumulate); G01 and accumulators f32.
//   out[b][m] = 0.5 + sum_{p,q} M_m[p][q] * G01[p] * G23[q]
__global__ __launch_bounds__(TPB) void qnn_fused(const float4* __restrict__ x,
                                                 const float* __restrict__ alpha,
                                                 const float* __restrict__ thetas,
                                                 float* __restrict__ out,
                                                 int batch, int nthreads) {
    __shared__ float2  csT[128];       // (cos,sin) of thetas/2
    __shared__ float2  csA[8];         // (cos,sin) of alpha/2
    __shared__ float   U[4][16][20];   // e[k]-scaled columns, rows padded to 20
    __shared__ float   w4s;            // tail weight sum
    __shared__ float   Af[3][16][16];  // full symmetric A_m
    __shared__ half2_t Mh[3][10][8];   // packed M rows: [m][p][qpair], 32B stride

    const int tid = threadIdx.x;
    const int gid = blockIdx.x * TPB + tid;

    // ---- prefetch samples (HBM latency hides under setup) ----
    float4 xv[SPT];
    #pragma unroll
    for (int s = 0; s < SPT; ++s) {
        const int b = gid + s * nthreads;
        xv[s] = x[(b < batch) ? b : 0];
    }

    // ---- phase 0: angle tables ----
    if (tid < 128) {
        const float t = thetas[tid] * 0.5f;
        csT[tid] = make_float2(cosf(t), sinf(t));
    } else if (tid < 135) {
        const float t = alpha[tid - 128] * 0.5f;
        csA[tid - 128] = make_float2(cosf(t), sinf(t));
    }

    // ---- per-sample G products (independent of LDS; overlaps setup) ----
    float G01[SPT][10], acc[SPT][3];
    half2_t gh[SPT][5];
    #pragma unroll
    for (int s = 0; s < SPT; ++s) {
        float c0, s0, c1, s1, c2, s2, c3, s3;
        sincospif(xv[s].x, &s0, &c0);
        sincospif(xv[s].y, &s1, &c1);
        sincospif(xv[s].z, &s2, &c2);
        sincospif(xv[s].w, &s3, &c3);
        float f01[4], f23[4];
        f01[0] = c0 * c1; f01[1] = c0 * s1; f01[2] = s0 * c1; f01[3] = s0 * s1;
        f23[0] = c2 * c3; f23[1] = c2 * s3; f23[2] = s2 * c3; f23[3] = s2 * s3;
        int idx = 0;
        #pragma unroll
        for (int i = 0; i < 4; ++i)
            #pragma unroll
            for (int k = i; k < 4; ++k) { G01[s][idx] = f01[i] * f01[k]; ++idx; }
        float G23[10];
        idx = 0;
        #pragma unroll
        for (int j = 0; j < 4; ++j)
            #pragma unroll
            for (int l = j; l < 4; ++l) { G23[idx] = f23[j] * f23[l]; ++idx; }
        #pragma unroll
        for (int j = 0; j < 5; ++j)
            gh[s][j] = __builtin_amdgcn_cvt_pkrtz(G23[2*j], G23[2*j + 1]);
        acc[s][0] = 0.5f; acc[s][1] = 0.5f; acc[s][2] = 0.5f;
    }
    __syncthreads();

    // ---- phase 1: lanes 0..63 simulate one scaled column each ----
    if (tid < 64) {
        float e[8];
        #pragma unroll
        for (int i = 0; i < 8; ++i) e[i] = (i == 0) ? 1.0f : 0.0f;
        int idx = 0;
        #pragma unroll
        for (int l = 0; l < 3; ++l) {
            const int p = 2 - l, pb = 1 << p;
            #pragma unroll
            for (int i0 = 0; i0 < 8; ++i0) {
                if (i0 & pb) continue;
                const int i1 = i0 | pb;
                const float2 cs = csA[idx + (i0 >> (p + 1))];
                const float a0 = e[i0], a1 = e[i1];
                e[i0] = cs.x * a0 - cs.y * a1;
                e[i1] = cs.y * a0 + cs.x * a1;
            }
            idx += (1 << l);
        }
        if (tid == 0)
            w4s = e[4]*e[4] + e[5]*e[5] + e[6]*e[6] + e[7]*e[7];

        const int k = tid >> 4, col = tid & 15;
        float st[16];
        #pragma unroll
        for (int i = 0; i < 16; ++i) st[i] = (i == col) ? 1.0f : 0.0f;
        #pragma unroll 1
        for (int l = 0; l < NLAY; ++l) {
            #pragma unroll
            for (int q = 0; q < 4; ++q) {
                const float2 cs = csT[k * 32 + l * 4 + q];
                const int pb = 1 << (3 - q);
                #pragma unroll
                for (int i0 = 0; i0 < 16; ++i0) {
                    if (i0 & pb) continue;
                    const int i1 = i0 | pb;
                    const float a0 = st[i0], a1 = st[i1];
                    st[i0] = cs.x * a0 - cs.y * a1;   // RY = [[c,-s],[s,c]]
                    st[i1] = cs.y * a0 + cs.x * a1;
                }
            }
            #pragma unroll
            for (int q = 0; q < 3; ++q) {   // CNOT(q,q+1): register renames
                const int cb = 1 << (3 - q), tb = 1 << (2 - q);
                #pragma unroll
                for (int i = 0; i < 16; ++i) {
                    if ((i & cb) && !(i & tb)) {
                        const int j = i | tb;
                        const float tmp = st[i]; st[i] = st[j]; st[j] = tmp;
                    }
                }
            }
        }
        const float sw = e[k];   // sign cancels in products
        float4* dst = (float4*)&U[k][col][0];
        dst[0] = make_float4(st[0]*sw,  st[1]*sw,  st[2]*sw,  st[3]*sw);
        dst[1] = make_float4(st[4]*sw,  st[5]*sw,  st[6]*sw,  st[7]*sw);
        dst[2] = make_float4(st[8]*sw,  st[9]*sw,  st[10]*sw, st[11]*sw);
        dst[3] = make_float4(st[12]*sw, st[13]*sw, st[14]*sw, st[15]*sw);
    }
    __syncthreads();

    // ---- phase 2a: symmetric A_m, 136 jobs ----
    if (tid < 136) {
        int r = tid, t = 0;
        while (r >= 16 - t) { r -= 16 - t; ++t; }
        const int u = t + r;

        float gs[8] = {0,0,0,0,0,0,0,0};
        #pragma unroll
        for (int k = 0; k < 4; ++k) {
            const float4* ct = (const float4*)&U[k][t][0];
            const float4* cu = (const float4*)&U[k][u][0];
            const float4 a0 = ct[0], a1 = ct[1], a2 = ct[2], a3 = ct[3];
            const float4 c0 = cu[0], c1 = cu[1], c2 = cu[2], c3 = cu[3];
            gs[0] = fmaf(a0.x, c0.x, gs[0]); gs[0] = fmaf(a0.y, c0.y, gs[0]);
            gs[1] = fmaf(a0.z, c0.z, gs[1]); gs[1] = fmaf(a0.w, c0.w, gs[1]);
            gs[2] = fmaf(a1.x, c1.x, gs[2]); gs[2] = fmaf(a1.y, c1.y, gs[2]);
            gs[3] = fmaf(a1.z, c1.z, gs[3]); gs[3] = fmaf(a1.w, c1.w, gs[3]);
            gs[4] = fmaf(a2.x, c2.x, gs[4]); gs[4] = fmaf(a2.y, c2.y, gs[4]);
            gs[5] = fmaf(a2.z, c2.z, gs[5]); gs[5] = fmaf(a2.w, c2.w, gs[5]);
            gs[6] = fmaf(a3.x, c3.x, gs[6]); gs[6] = fmaf(a3.y, c3.y, gs[6]);
            gs[7] = fmaf(a3.z, c3.z, gs[7]); gs[7] = fmaf(a3.w, c3.w, gs[7]);
        }
        float A0 = 0.f, A1 = 0.f, A2 = 0.f;
        #pragma unroll
        for (int c = 0; c < 8; ++c) {
            const float g = gs[c];
            A0 += (c & 4) ? -g : g;
            A1 += (c & 2) ? -g : g;
            A2 += (c & 1) ? -g : g;
        }
        if (t == u) {
            const float w4 = w4s;
            A0 += ((t >> 3) & 1) ? -w4 : w4;
            A1 += ((t >> 2) & 1) ? -w4 : w4;
            A2 += ((t >> 1) & 1) ? -w4 : w4;
        }
        Af[0][t][u] = A0; Af[0][u][t] = A0;
        Af[1][t][u] = A1; Af[1][u][t] = A1;
        Af[2][t][u] = A2; Af[2][u][t] = A2;
    }
    __syncthreads();

    // ---- phase 2b: fold + f16-pack to Mh (150 jobs, one q-pair each) ----
    if (tid < 150) {
        const int m = tid / 50, rr = tid - m * 50, p = rr / 5, jp = rr - p * 5;
        int i, k;
        if (p < 4)      { i = 0; k = p; }
        else if (p < 7) { i = 1; k = p - 3; }
        else if (p < 9) { i = 2; k = p - 5; }
        else            { i = 3; k = 3; }
        float v[2];
        #pragma unroll
        for (int h = 0; h < 2; ++h) {
            const int q = 2 * jp + h;
            int jj, ll;
            if (q < 4)      { jj = 0; ll = q; }
            else if (q < 7) { jj = 1; ll = q - 3; }
            else if (q < 9) { jj = 2; ll = q - 5; }
            else            { jj = 3; ll = 3; }
            if (i < k && jj < ll)       v[h] = Af[m][4*i+jj][4*k+ll] + Af[m][4*i+ll][4*k+jj];
            else if (i == k && jj < ll) v[h] = Af[m][4*i+jj][4*i+ll];
            else if (i < k && jj == ll) v[h] = Af[m][4*i+jj][4*k+jj];
            else                        v[h] = 0.5f * Af[m][4*i+jj][4*i+jj];
        }
        Mh[m][p][jp] = __builtin_amdgcn_cvt_pkrtz(v[0], v[1]);
    }
    __syncthreads();

    // ---- phase 3: per p, 6 batched LDS reads + 6 independent dot2 chains ----
    #pragma unroll
    for (int p = 0; p < 10; ++p) {
        const int4 i0 = *(const int4*)&Mh[0][p][0];
        const int  t0 = *(const int*)&Mh[0][p][4];
        const int4 i1 = *(const int4*)&Mh[1][p][0];
        const int  t1 = *(const int*)&Mh[1][p][4];
        const int4 i2 = *(const int4*)&Mh[2][p][0];
        const int  t2 = *(const int*)&Mh[2][p][4];
        const half2_t h00 = bch(i0.x), h01 = bch(i0.y), h02 = bch(i0.z), h03 = bch(i0.w), h04 = bch(t0);
        const half2_t h10 = bch(i1.x), h11 = bch(i1.y), h12 = bch(i1.z), h13 = bch(i1.w), h14 = bch(t1);
        const half2_t h20 = bch(i2.x), h21 = bch(i2.y), h22 = bch(i2.z), h23 = bch(i2.w), h24 = bch(t2);
        #pragma unroll
        for (int s = 0; s < SPT; ++s) {
            float z0 = __builtin_amdgcn_fdot2(h00, gh[s][0], 0.0f, false);
            float z1 = __builtin_amdgcn_fdot2(h10, gh[s][0], 0.0f, false);
            float z2 = __builtin_amdgcn_fdot2(h20, gh[s][0], 0.0f, false);
            z0 = __builtin_amdgcn_fdot2(h01, gh[s][1], z0, false);
            z1 = __builtin_amdgcn_fdot2(h11, gh[s][1], z1, false);
            z2 = __builtin_amdgcn_fdot2(h21, gh[s][1], z2, false);
            z0 = __builtin_amdgcn_fdot2(h02, gh[s][2], z0, false);
            z1 = __builtin_amdgcn_fdot2(h12, gh[s][2], z1, false);
            z2 = __builtin_amdgcn_fdot2(h22, gh[s][2], z2, false);
            z0 = __builtin_amdgcn_fdot2(h03, gh[s][3], z0, false);
            z1 = __builtin_amdgcn_fdot2(h13, gh[s][3], z1, false);
            z2 = __builtin_amdgcn_fdot2(h23, gh[s][3], z2, false);
            z0 = __builtin_amdgcn_fdot2(h04, gh[s][4], z0, false);
            z1 = __builtin_amdgcn_fdot2(h14, gh[s][4], z1, false);
            z2 = __builtin_amdgcn_fdot2(h24, gh[s][4], z2, false);
            acc[s][0] = fmaf(G01[s][p], z0, acc[s][0]);
            acc[s][1] = fmaf(G01[s][p], z1, acc[s][1]);
            acc[s][2] = fmaf(G01[s][p], z2, acc[s][2]);
        }
    }

    #pragma unroll
    for (int s = 0; s < SPT; ++s) {
        const int b = gid + s * nthreads;
        if (b < batch) {
            out[b * 3 + 0] = acc[s][0];
            out[b * 3 + 1] = acc[s][1];
            out[b * 3 + 2] = acc[s][2];
        }
    }
}

extern "C" void kernel_launch(void* const* d_in, const int* in_sizes, int n_in,
                              void* d_out, int out_size, void* d_ws, size_t ws_size,
                              hipStream_t stream) {
    const float* x      = (const float*)d_in[0];   // (131072, 4) f32
    const float* alpha  = (const float*)d_in[1];   // (7,) f32
    const float* thetas = (const float*)d_in[2];   // (4, 32) f32

    const int batch = in_sizes[0] / 4;                         // 131072
    const int blocks = (batch + TPB * SPT - 1) / (TPB * SPT);  // 256
    const int nthreads = blocks * TPB;
    qnn_fused<<<blocks, TPB, 0, stream>>>((const float4*)x, alpha, thetas,
                                          (float*)d_out, batch, nthreads);
}